// Round 8
// baseline (150.923 us; speedup 1.0000x reference)
//
#include <hip/hip_runtime.h>
#include <cstdint>
#include <cstddef>

typedef __bf16 bf16;
typedef __attribute__((ext_vector_type(4))) __bf16 bf16x4;
typedef __attribute__((ext_vector_type(8))) __bf16 bf16x8;
typedef __attribute__((ext_vector_type(4))) float f32x4;

#define EPS_C 1e-4f
#define SWZ(r) (((r) ^ ((r) >> 2)) & 3)

// light barrier: LDS visibility only, vmem loads stay in flight (no vmcnt drain)
#define BAR_LDS() do { asm volatile("s_waitcnt lgkmcnt(0)" ::: "memory"); \
                       __builtin_amdgcn_s_barrier(); } while (0)

// ================= K0: weights prep + conv tables + zero page =================
__global__ __launch_bounds__(256) void k0_prep(const float* __restrict__ Wi,
    const float* __restrict__ Wo, const float* __restrict__ cw, const float* __restrict__ cb,
    bf16* __restrict__ Whg, bf16* __restrict__ Wlg, bf16* __restrict__ Wob,
    float* __restrict__ cwT, float* __restrict__ cbl, float* __restrict__ zpg)
{
    int idx = blockIdx.x * 256 + threadIdx.x;
    if (idx < 196608) {
        int n = idx >> 10, k = idx & 1023;
        float w;
        if (n < 64) {
            w = Wi[n * 1024 + k];
        } else if (n < 128) {
            int i = n - 64;
            w = 0.5f * (Wi[(64 + 2 * i) * 1024 + k] + Wi[(65 + 2 * i) * 1024 + k]);
        } else {
            int i = n - 128;
            w = 0.5f * (Wi[(192 + 2 * i) * 1024 + k] + Wi[(193 + 2 * i) * 1024 + k]);
        }
        bf16 h = (bf16)w;
        int dst = (k >> 5) * 6144 + n * 32 + (k & 31);
        Whg[dst] = h;
        Wlg[dst] = (bf16)(w - (float)h);
    } else if (idx < 262144) {
        int j = idx - 196608;
        Wob[j] = (bf16)Wo[j];
    } else if (idx < 266240) {
        int j = idx - 262144;                 // cwT[tap][ch] tap-major
        int tap = j >> 10, ch = j & 1023;
        cwT[j] = cw[ch * 4 + tap];
    } else if (idx < 267264) {
        int j = idx - 266240;
        cbl[j] = cb[j];
    } else {
        int j = idx - 267264;
        if (j < 256) { f32x4 z = {0.f, 0.f, 0.f, 0.f}; ((f32x4*)zpg)[j] = z; }
    }
}

// ================= K1: conv + split-bf16 MFMA in_proj + SSM + chunk-local scan =================
// 256 threads (4 waves), 3 blocks/CU. Block: 32t x 192n, BK=32, 32 chunks.
// x staged in 128-ch batches (512B-contiguous per t-row -> wide HBM bursts) into
// raw[2][35][128]f32; conv reads taps from raw; xc hi/lo dbuf; W direct global->reg.
__global__ __launch_bounds__(256, 3) void k1_convproj(
    const float* __restrict__ x, const float* __restrict__ in_proj_b,
    const float* __restrict__ A_log,
    const bf16* __restrict__ Whg, const bf16* __restrict__ Wlg,
    const float* __restrict__ cwT, const float* __restrict__ cbl,
    const float* __restrict__ zpg,
    float* __restrict__ Yp, float* __restrict__ Zp,
    float* __restrict__ Psum, float* __restrict__ Ssum)
{
    __shared__ char smem[44032];
    // raw0 @0 (17920) | raw1 @17920 (ends 35840)
    // xch: buf0 @35840, buf1 @37888 | xcl: buf0 @39936, buf1 @41984 (ends 44032)
    // epilogue overlay: res f32 [32][196] @0 (25088), part @25088 (2048)

    const int tid  = threadIdx.x;
    const int lane = tid & 63;
    const int wn   = tid >> 6;               // wave = n-quarter
    const int fr   = lane & 15, fs = lane >> 4;
    const int b    = blockIdx.x >> 7;
    const int tc   = blockIdx.x & 127;
    const int t0   = tc * 32;

    // conv mapping: thread -> (t-row ct, 4-ch slot cs)
    const int ct = tid >> 3, cs = tid & 7;
    const int gt = t0 + ct;
    const bool zrow = (gt == 4095);          // reference zero-pads last conv row
    const int xwo = ct * 64 + ((((cs >> 1) ^ SWZ(ct)) & 3) << 4) + (cs & 1) * 8;

    int aoff[2];
#pragma unroll
    for (int mi = 0; mi < 2; ++mi) {
        int r = mi * 16 + fr;
        aoff[mi] = r * 64 + ((fs ^ SWZ(r)) << 4);
    }

    // W fragment base within a chunk
    const size_t wfo = (size_t)(wn * 48 + fr) * 32 + fs * 8;

    // staging mapping: thread -> (row = (tid>>5)+8j, 16B-quad q32 = tid&31)
    const int srow_s = tid >> 5, q32 = tid & 31;
    const float* rp[5];
    int  rowv[5];
    bool wrk[5];
#pragma unroll
    for (int j = 0; j < 5; ++j) {
        int row = srow_s + j * 8;
        rowv[j] = row;
        wrk[j]  = (row < 35);
        int g = t0 - 1 + row;
        rp[j] = (wrk[j] && g >= 0 && g < 4096)
              ? x + ((size_t)b * 4096 + g) * 1024 + q32 * 4
              : zpg + q32 * 4;               // zpg holds >=1024 zero floats
    }

    f32x4  xs[5];
    bf16x8 wfa[6], wfb[6];
    f32x4  acc[2][3] = {};

    auto fetch_batch = [&](int q) {          // issue 512B-per-row global loads
#pragma unroll
        for (int j = 0; j < 5; ++j)
            xs[j] = *(const f32x4*)(rp[j] + q * 128);
    };
    auto raw_write = [&](int q) {
        char* rb = smem + (q & 1) * 17920;
#pragma unroll
        for (int j = 0; j < 5; ++j)
            if (wrk[j]) *(f32x4*)(rb + rowv[j] * 512 + q32 * 16) = xs[j];
    };
    auto fetch_w = [&](int c, bf16x8 (&wf)[6]) {
        const bf16* ph = Whg + (size_t)c * 6144 + wfo;
        const bf16* pl = Wlg + (size_t)c * 6144 + wfo;
#pragma unroll
        for (int ni = 0; ni < 3; ++ni) {
            wf[ni]     = *(const bf16x8*)(ph + ni * 512);
            wf[3 + ni] = *(const bf16x8*)(pl + ni * 512);
        }
    };
    auto conv_chunk = [&](int cc) {          // raw[(cc>>2)&1] -> xc[cc&1]
        const char* rb = smem + ((cc >> 2) & 1) * 17920;
        char* dh = smem + 35840 + (cc & 1) * 2048;
        char* dl = smem + 39936 + (cc & 1) * 2048;
        const int sub = cc & 3;
        const int ch0 = cc * 32 + cs * 4;
        f32x4 v = *(const f32x4*)&cbl[ch0];  // L1-hot tables
#pragma unroll
        for (int dt = 0; dt < 4; ++dt) {
            f32x4 w  = *(const f32x4*)&cwT[dt * 1024 + ch0];
            f32x4 xt = *(const f32x4*)(rb + (ct + dt) * 512 + sub * 128 + cs * 16);
            v.x = fmaf(w.x, xt.x, v.x);
            v.y = fmaf(w.y, xt.y, v.y);
            v.z = fmaf(w.z, xt.z, v.z);
            v.w = fmaf(w.w, xt.w, v.w);
        }
        bf16x4 hi, lo;
#pragma unroll
        for (int j = 0; j < 4; ++j) {
            float vv = zrow ? 0.f : v[j];
            bf16 h = (bf16)vv;
            hi[j] = h;
            lo[j] = (bf16)(vv - (float)h);
        }
        *(bf16x4*)(dh + xwo) = hi;
        *(bf16x4*)(dl + xwo) = lo;
    };

    // ---- prologue ----
    fetch_batch(0);
    fetch_w(0, wfa);
    raw_write(0);                            // waits on batch-0 loads
    fetch_batch(1);                          // stays in flight
    BAR_LDS();                               // raw0 visible
    conv_chunk(0);
    fetch_w(1, wfb);
    BAR_LDS();                               // xc0 visible

    auto body = [&](int c, bf16x8 (&wf)[6]) {
        const int par = c & 1;
        const char* xh = smem + 35840 + par * 2048;
        const char* xl = smem + 39936 + par * 2048;
        bf16x8 ah0 = *(const bf16x8*)(xh + aoff[0]);
        bf16x8 ah1 = *(const bf16x8*)(xh + aoff[1]);
        bf16x8 al0 = *(const bf16x8*)(xl + aoff[0]);
        bf16x8 al1 = *(const bf16x8*)(xl + aoff[1]);
        if ((c & 3) == 0 && c > 0 && (c >> 2) < 7)
            fetch_batch((c >> 2) + 1);       // 512B bursts, 2-body flight
        __builtin_amdgcn_s_setprio(1);
#pragma unroll
        for (int ni = 0; ni < 3; ++ni) {
            bf16x8 bh = wf[ni], bl = wf[3 + ni];
            acc[0][ni] = __builtin_amdgcn_mfma_f32_16x16x32_bf16(ah0, bh, acc[0][ni], 0, 0, 0);
            acc[1][ni] = __builtin_amdgcn_mfma_f32_16x16x32_bf16(ah1, bh, acc[1][ni], 0, 0, 0);
            acc[0][ni] = __builtin_amdgcn_mfma_f32_16x16x32_bf16(al0, bh, acc[0][ni], 0, 0, 0);
            acc[1][ni] = __builtin_amdgcn_mfma_f32_16x16x32_bf16(al1, bh, acc[1][ni], 0, 0, 0);
            acc[0][ni] = __builtin_amdgcn_mfma_f32_16x16x32_bf16(ah0, bl, acc[0][ni], 0, 0, 0);
            acc[1][ni] = __builtin_amdgcn_mfma_f32_16x16x32_bf16(ah1, bl, acc[1][ni], 0, 0, 0);
        }
        __builtin_amdgcn_s_setprio(0);
        if ((c & 3) == 2 && (c >> 2) < 7)
            raw_write((c >> 2) + 1);         // next batch -> idle raw buffer
        if (c + 2 < 32) fetch_w(c + 2, wf);
        if (c + 1 < 32) conv_chunk(c + 1);
        BAR_LDS();
    };

#pragma unroll 1
    for (int cc = 0; cc < 32; cc += 2) {
        body(cc,     wfa);
        body(cc + 1, wfb);
    }

    // ---- epilogue: acc -> res[32][196], SSM elementwise + chunk-local scan ----
    float* res = (float*)smem;
#pragma unroll
    for (int mi = 0; mi < 2; ++mi)
#pragma unroll
        for (int ni = 0; ni < 3; ++ni) {
            int col = wn * 48 + ni * 16 + fr;
#pragma unroll
            for (int r = 0; r < 4; ++r)
                res[(mi * 16 + fs * 4 + r) * 196 + col] = acc[mi][ni][r];
        }
    __syncthreads();

    float* part = (float*)(smem + 25088);    // [2][4][64]
    const int i  = lane;
    const int tg = tid >> 6;
    const float A  = -expf(A_log[i]);
    const float bd = in_proj_b[i];
    const float bB = 0.5f * (in_proj_b[64 + 2 * i] + in_proj_b[65 + 2 * i]);
    const float bC = 0.5f * (in_proj_b[192 + 2 * i] + in_proj_b[193 + 2 * i]);
    const bool tiny = fabsf(A) < EPS_C;
    float av[8], bv[8], cv[8];
#pragma unroll
    for (int r = 0; r < 8; ++r) {
        int t = tg * 8 + r;
        float d  = res[t * 196 + i] + bd;
        float Bm = res[t * 196 + 64 + i] + bB;
        float Cm = res[t * 196 + 128 + i] + bC;
        float delta = (d > 20.f) ? d : log1pf(expf(d));
        float dA = delta * A;
        float abar = expf(dA);
        float sc = tiny ? (1.f + dA * 0.5f + dA * dA * (1.f / 6.f)) : ((abar - 1.f) / A);
        av[r] = abar; bv[r] = sc * Bm; cv[r] = Cm;
    }
    float P = 1.f, S = 0.f;
#pragma unroll
    for (int r = 0; r < 8; ++r) { S = fmaf(av[r], S, bv[r]); P *= av[r]; }
    part[tg * 64 + i] = P;
    part[256 + tg * 64 + i] = S;
    __syncthreads();
    float h = 0.f, pp = 1.f;
#pragma unroll
    for (int g = 0; g < 3; ++g)
        if (g < tg) {
            float Pg = part[g * 64 + i], Sg = part[256 + g * 64 + i];
            h = fmaf(Pg, h, Sg);
            pp *= Pg;
        }
    size_t ob = ((size_t)b * 4096 + t0 + tg * 8) * 64 + i;
#pragma unroll
    for (int r = 0; r < 8; ++r) {
        h  = fmaf(av[r], h, bv[r]);          // chunk-local state
        pp *= av[r];                         // chunk-local prefix product
        Yp[ob + (size_t)r * 64] = cv[r] * h;
        Zp[ob + (size_t)r * 64] = cv[r] * pp;
    }
    if (tg == 3) {
        size_t o = ((size_t)b * 128 + tc) * 64 + i;
        Psum[o] = pp;
        Ssum[o] = h;
    }
}

// ================= K2: serial carry combine across 128 chunks =================
__global__ __launch_bounds__(64) void k2_scan2(const float* __restrict__ Psum,
    const float* __restrict__ Ssum, float* __restrict__ Carry)
{
    int b = blockIdx.x, i = threadIdx.x;
    float h = 0.f;
#pragma unroll 1
    for (int g = 0; g < 8; ++g) {
        size_t base = ((size_t)b * 128 + g * 16) * 64 + i;
        float Pv[16], Sv[16];
#pragma unroll
        for (int j = 0; j < 16; ++j) {
            Pv[j] = Psum[base + (size_t)j * 64];
            Sv[j] = Ssum[base + (size_t)j * 64];
        }
#pragma unroll
        for (int j = 0; j < 16; ++j) {
            Carry[base + (size_t)j * 64] = h;
            h = fmaf(Pv[j], h, Sv[j]);
        }
    }
}

// ================= K3: y = Yp + Zp*carry, fused out_proj MFMA =================
// 512 threads (8 waves). Block = 32-t chunk; wave: 32t x 128n.
__global__ __launch_bounds__(512) void k3_scan_out(
    const float* __restrict__ Yp, const float* __restrict__ Zp,
    const float* __restrict__ Carry, const bf16* __restrict__ Wob,
    const float* __restrict__ bo, float* __restrict__ out)
{
    __shared__ char sm3[4096];               // [32 t][64 i] bf16, swizzled

    const int tid  = threadIdx.x;
    const int lane = tid & 63;
    const int wv   = tid >> 6;
    const int b    = blockIdx.x >> 7;
    const int ch   = blockIdx.x & 127;
    const int t0   = ch * 32;

    const int i = lane, tg = wv;
    float cr = Carry[((size_t)b * 128 + ch) * 64 + i];
    size_t base = ((size_t)b * 4096 + t0 + tg * 4) * 64 + i;
#pragma unroll
    for (int r = 0; r < 4; ++r) {
        float y = Yp[base + (size_t)r * 64] + Zp[base + (size_t)r * 64] * cr;
        int t = tg * 4 + r;
        int off = t * 128 + ((((i >> 3) ^ (t & 7)) & 7) << 4) + (i & 7) * 2;
        *(bf16*)(sm3 + off) = (bf16)y;
    }
    __syncthreads();

    const int fr = lane & 15, fs = lane >> 4;
    bf16x8 afr[2][2];
#pragma unroll
    for (int mi = 0; mi < 2; ++mi)
#pragma unroll
        for (int ks = 0; ks < 2; ++ks) {
            int row = mi * 16 + fr;
            int slot = ks * 4 + fs;
            int off = row * 128 + (((slot ^ (row & 7)) & 7) << 4);
            afr[mi][ks] = *(const bf16x8*)(sm3 + off);
        }
    const int n0 = wv * 128;
#pragma unroll
    for (int ni = 0; ni < 8; ++ni) {
        int col = n0 + ni * 16 + fr;
        bf16x8 b0 = *(const bf16x8*)(Wob + (size_t)col * 64 + fs * 8);
        bf16x8 b1 = *(const bf16x8*)(Wob + (size_t)col * 64 + 32 + fs * 8);
        float bias = bo[col];
#pragma unroll
        for (int mi = 0; mi < 2; ++mi) {
            f32x4 a = {};
            a = __builtin_amdgcn_mfma_f32_16x16x32_bf16(afr[mi][0], b0, a, 0, 0, 0);
            a = __builtin_amdgcn_mfma_f32_16x16x32_bf16(afr[mi][1], b1, a, 0, 0, 0);
#pragma unroll
            for (int r = 0; r < 4; ++r) {
                int t = mi * 16 + fs * 4 + r;
                out[((size_t)b * 4096 + t0 + t) * 1024 + col] = a[r] + bias;
            }
        }
    }
}

extern "C" void kernel_launch(void* const* d_in, const int* in_sizes, int n_in,
                              void* d_out, int out_size, void* d_ws, size_t ws_size,
                              hipStream_t stream) {
    const float* x          = (const float*)d_in[0];
    const float* conv_w     = (const float*)d_in[1];
    const float* conv_b     = (const float*)d_in[2];
    const float* in_proj_w  = (const float*)d_in[3];
    const float* in_proj_b  = (const float*)d_in[4];
    const float* A_log      = (const float*)d_in[5];
    const float* out_proj_w = (const float*)d_in[6];
    const float* out_proj_b = (const float*)d_in[7];
    float* out = (float*)d_out;

    char* w = (char*)d_ws;
    bf16*  Whg  = (bf16*)w;                                    // 393216 B
    bf16*  Wlg  = (bf16*)(w + 393216);                         // 393216 B
    bf16*  Wob  = (bf16*)(w + 786432);                         // 131072 B
    float* Yp   = (float*)(w + 917504);                        // 8 MiB
    float* Zp   = (float*)(w + 917504 + 8388608);              // 8 MiB
    float* Psum = (float*)(w + 917504 + 2 * 8388608);          // 128 KiB used
    float* Ssum = (float*)(w + 917504 + 2 * 8388608 + 262144);
    float* Carry= (float*)(w + 917504 + 2 * 8388608 + 524288);
    float* zpg  = (float*)(w + 917504 + 2 * 8388608 + 786432); // 4 KiB zeroed
    float* cwT  = (float*)(w + 917504 + 2 * 8388608 + 794624); // 16 KiB
    float* cbl  = (float*)(w + 917504 + 2 * 8388608 + 811008); // 4 KiB

    hipLaunchKernelGGL(k0_prep,     dim3(1045), dim3(256), 0, stream,
                       in_proj_w, out_proj_w, conv_w, conv_b,
                       Whg, Wlg, Wob, cwT, cbl, zpg);
    hipLaunchKernelGGL(k1_convproj, dim3(1024), dim3(256), 0, stream,
                       x, in_proj_b, A_log, Whg, Wlg, cwT, cbl, zpg,
                       Yp, Zp, Psum, Ssum);
    hipLaunchKernelGGL(k2_scan2,    dim3(8),    dim3(64),  0, stream, Psum, Ssum, Carry);
    hipLaunchKernelGGL(k3_scan_out, dim3(1024), dim3(512), 0, stream,
                       Yp, Zp, Carry, Wob, out_proj_b, out);
}